// Round 1
// baseline (4814.252 us; speedup 1.0000x reference)
//
#include <hip/hip_runtime.h>
#include <cstdint>
#include <cstddef>

// ===========================================================================
// ActionDecoder: embed+concat -> precomputed input projections ->
// 512-step LSTM recurrence (grid-resident, LDS-resident W_hh slices,
// grid barrier per step) -> last-valid-step hidden -> action head GEMM.
//
// Partition: 64 WGs, WG k owns h columns [8k, 8k+8) => 32 rows of W_hh
// (i,f,g,o x 8) kept in LDS as f16 for all 512 steps. Per step each WG
// stages full h_t (64x512 f16) from a double-buffered global array,
// computes S[64,32] = h_t @ Wsliceᵀ with mfma_f32_16x16x32_f16, applies
// gates in f32, writes its h slice + grid barrier.
// ===========================================================================

typedef _Float16 f16x8 __attribute__((ext_vector_type(8)));
typedef float    f32x4 __attribute__((ext_vector_type(4)));

#define TPB 256
#define NWG 64

// ---- ws layout (bytes) ----
#define WS_GX0   0          // 64*2048 f32   = 524288
#define WS_P     524288     // 512*2048 f32  = 4194304
#define WS_HN    4718592    // 64*512 f32    = 131072
#define WS_HBUF  4849664    // 2*64*512 f16  = 131072
#define WS_CTR   4980736    // counter

__device__ __forceinline__ float sigm_(float x) { return 1.f / (1.f + __expf(-x)); }
__device__ __forceinline__ float tanh_(float x) {
    const float e = __expf(-2.f * fabsf(x));
    return copysignf((1.f - e) / (1.f + e), x);
}

// grid barrier: monotonic counter, agent scope release/acquire.
__device__ __forceinline__ void gbar(unsigned int* c, unsigned int target) {
    __syncthreads();
    if (threadIdx.x == 0) {
        __hip_atomic_fetch_add(c, 1u, __ATOMIC_ACQ_REL, __HIP_MEMORY_SCOPE_AGENT);
        while (__hip_atomic_load(c, __ATOMIC_ACQUIRE, __HIP_MEMORY_SCOPE_AGENT) < target)
            __builtin_amdgcn_s_sleep(1);
    }
    __syncthreads();
}

// ---------------------------------------------------------------------------
// Generic f32 tiled GEMM: C[M,N] = A[M,K] @ B[N,K]^T (+bias1+bias2 on z==0).
// 64x64 tile, 4x4 micro-tile, K split across gridDim.z (atomicAdd if z>1).
// All dims used here divide evenly (no edge guards needed).
// ---------------------------------------------------------------------------
__global__ void gemm_nt_bias(const float* __restrict__ A, int lda,
                             const float* __restrict__ B, int ldb,
                             float* __restrict__ C, int ldc, int K,
                             const float* __restrict__ bias1,
                             const float* __restrict__ bias2)
{
    __shared__ float As[32 * 68];   // transposed: As[kk*68 + r]
    __shared__ float Bs[32 * 68];
    const int tid = threadIdx.x;
    const int m0 = blockIdx.y * 64, n0 = blockIdx.x * 64;
    const int kchunk = K / gridDim.z;
    const int kbeg = blockIdx.z * kchunk, kend = kbeg + kchunk;
    const int tr = tid >> 4, tc = tid & 15;
    float acc[4][4] = {};

    for (int k0 = kbeg; k0 < kend; k0 += 32) {
        __syncthreads();
        #pragma unroll
        for (int idx = tid; idx < 2048; idx += TPB) {
            const int r = idx >> 5, kk = idx & 31;
            As[kk * 68 + r] = A[(size_t)(m0 + r) * lda + k0 + kk];
            Bs[kk * 68 + r] = B[(size_t)(n0 + r) * ldb + k0 + kk];
        }
        __syncthreads();
        #pragma unroll
        for (int kk = 0; kk < 32; ++kk) {
            const f32x4 a = *(const f32x4*)&As[kk * 68 + tr * 4];
            const f32x4 b = *(const f32x4*)&Bs[kk * 68 + tc * 4];
            #pragma unroll
            for (int i = 0; i < 4; ++i)
                #pragma unroll
                for (int j = 0; j < 4; ++j)
                    acc[i][j] = fmaf(a[i], b[j], acc[i][j]);
        }
    }

    const bool split = (gridDim.z > 1);
    #pragma unroll
    for (int i = 0; i < 4; ++i) {
        const int m = m0 + tr * 4 + i;
        #pragma unroll
        for (int j = 0; j < 4; ++j) {
            const int n = n0 + tc * 4 + j;
            float v = acc[i][j];
            if (blockIdx.z == 0) {
                if (bias1) v += bias1[n];
                if (bias2) v += bias2[n];
            }
            if (split) atomicAdd(&C[(size_t)m * ldc + n], v);
            else       C[(size_t)m * ldc + n] = v;
        }
    }
}

// ---------------------------------------------------------------------------
// LSTM recurrence. grid = 64 WGs x 256 threads (4 waves), 1 WG per CU.
// ---------------------------------------------------------------------------
__device__ __forceinline__ void gate_update(
    int t, int b, int q, int j0, float& c, int lastt,
    const float* Sl, const float* __restrict__ GX0,
    const float* __restrict__ P, const int* __restrict__ x2,
    _Float16* __restrict__ hdst, float* __restrict__ hn)
{
    const int tok = x2[b * 512 + t];
    const float* gx = GX0 + b * 2048;
    const float* pp = P + (size_t)tok * 2048;
    const int col = j0 + q;
    const float* s = Sl + b * 36;
    float iv = s[q]      + gx[col]        + pp[col];
    float fv = s[8 + q]  + gx[512 + col]  + pp[512 + col];
    float gv = s[16 + q] + gx[1024 + col] + pp[1024 + col];
    float ov = s[24 + q] + gx[1536 + col] + pp[1536 + col];
    iv = sigm_(iv); fv = sigm_(fv); gv = tanh_(gv); ov = sigm_(ov);
    c = fv * c + iv * gv;
    const float h = ov * tanh_(c);
    hdst[b * 512 + col] = (_Float16)h;
    if (t == lastt) hn[b * 512 + col] = h;   // f32, pre-quantization
}

__global__ void __launch_bounds__(TPB)
lstm_seq(const float* __restrict__ Whh,   // [2048,512] f32
         const float* __restrict__ GX0,   // [64,2048] f32 (ws)
         const float* __restrict__ P,     // [512,2048] f32 (ws)
         const int*   __restrict__ x2,    // [64,512]
         const int*   __restrict__ lens,  // [64]
         _Float16*    hbuf,               // [2][64*512] f16 (ws)
         float*       __restrict__ hn,    // [64,512] f32 (ws)
         unsigned int* counter)
{
    constexpr int H = 512, T = 512, BATCH = 64;
    constexpr int HP = 520;               // padded LDS pitch (f16 elems), 16B-aligned rows
    __shared__ _Float16 Wl[32 * HP];      // W_hh slice, f16      (33280 B)
    __shared__ _Float16 hl[BATCH * HP];   // staged h_t           (66560 B)
    __shared__ float    Sl[BATCH * 36];   // S = h @ Wsliceᵀ      ( 9216 B)

    const int tid = threadIdx.x;
    const int wg  = blockIdx.x;
    const int lane = tid & 63, wv = tid >> 6;
    const int j0 = wg * 8;

    // one-time: convert my 32 W_hh rows to f16 in LDS.
    // slice row s -> global gate row (s>>3)*512 + j0 + (s&7)   (i,f,g,o x 8)
    #pragma unroll
    for (int idx = tid; idx < 32 * 512; idx += TPB) {
        const int s = idx >> 9, kk = idx & 511;
        const int gr = (s >> 3) * 512 + j0 + (s & 7);
        Wl[s * HP + kk] = (_Float16)Whh[(size_t)gr * 512 + kk];
    }
    // zero my slice of hbuf[0] (h_0 = 0; ws is poisoned each launch)
    for (int idx = tid; idx < 512; idx += TPB)
        hbuf[wg * 512 + idx] = (_Float16)0.f;

    // persistent per-thread state: 2 (b, j) pairs, c in registers
    const int b0 = tid >> 3,          q0 = tid & 7;
    const int b1 = (tid + TPB) >> 3,  q1 = (tid + TPB) & 7;
    const int last0 = lens[b0] - 1, last1 = lens[b1] - 1;
    float c0 = 0.f, c1 = 0.f;

    unsigned int phase = 0;
    gbar(counter, ++phase * NWG);         // hbuf[0] zeros visible everywhere

    for (int t = 0; t < T; ++t) {
        const _Float16* hsrc = hbuf + (t & 1) * (BATCH * H);
        _Float16*       hdst = hbuf + ((t + 1) & 1) * (BATCH * H);

        // stage h_t into LDS, 16B per lane, coalesced
        #pragma unroll
        for (int idx = tid; idx < BATCH * H / 8; idx += TPB) {
            const int b = idx >> 6, off = (idx & 63) << 3;
            *(f16x8*)&hl[b * HP + off] = *(const f16x8*)&hsrc[b * H + off];
        }
        __syncthreads();

        // S[64x32] = h_t[64x512] @ Wsliceᵀ ; wave wv -> batch rows [16wv,16wv+16)
        f32x4 acc0 = {0.f, 0.f, 0.f, 0.f}, acc1 = {0.f, 0.f, 0.f, 0.f};
        {
            const int m = lane & 15, q = lane >> 4;
            const _Float16* aP  = &hl[(wv * 16 + m) * HP + q * 8];
            const _Float16* bP0 = &Wl[m * HP + q * 8];
            const _Float16* bP1 = &Wl[(16 + m) * HP + q * 8];
            #pragma unroll
            for (int ks = 0; ks < 16; ++ks) {
                const f16x8 af  = *(const f16x8*)(aP  + ks * 32);
                const f16x8 bf0 = *(const f16x8*)(bP0 + ks * 32);
                const f16x8 bf1 = *(const f16x8*)(bP1 + ks * 32);
                acc0 = __builtin_amdgcn_mfma_f32_16x16x32_f16(af, bf0, acc0, 0, 0, 0);
                acc1 = __builtin_amdgcn_mfma_f32_16x16x32_f16(af, bf1, acc1, 0, 0, 0);
            }
        }
        {   // D layout: row = (lane>>4)*4 + reg (batch), col = lane&15 (gate)
            const int cl = lane & 15, r0 = (lane >> 4) * 4;
            #pragma unroll
            for (int r = 0; r < 4; ++r) {
                Sl[(wv * 16 + r0 + r) * 36 + cl]      = acc0[r];
                Sl[(wv * 16 + r0 + r) * 36 + 16 + cl] = acc1[r];
            }
        }
        __syncthreads();

        gate_update(t, b0, q0, j0, c0, last0, Sl, GX0, P, x2, hdst, hn);
        gate_update(t, b1, q1, j0, c1, last1, Sl, GX0, P, x2, hdst, hn);

        gbar(counter, ++phase * NWG);     // h_{t+1} published
    }
}

// ---------------------------------------------------------------------------
extern "C" void kernel_launch(void* const* d_in, const int* in_sizes, int n_in,
                              void* d_out, int out_size, void* d_ws, size_t ws_size,
                              hipStream_t stream)
{
    const float* x1    = (const float*)d_in[0];   // [64,1024]
    const int*   x2    = (const int*)  d_in[1];   // [64,512]
    const int*   lens  = (const int*)  d_in[2];   // [64]
    const float* emb   = (const float*)d_in[3];   // [512,128]
    const float* W_ih  = (const float*)d_in[4];   // [2048,1152]
    const float* W_hh  = (const float*)d_in[5];   // [2048,512]
    const float* b_ih  = (const float*)d_in[6];   // [2048]
    const float* b_hh  = (const float*)d_in[7];   // [2048]
    const float* W_act = (const float*)d_in[8];   // [512,512]
    const float* b_act = (const float*)d_in[9];   // [512]
    float* out = (float*)d_out;                   // [64,512]

    char* ws = (char*)d_ws;
    float*        GX0     = (float*)(ws + WS_GX0);
    float*        P       = (float*)(ws + WS_P);
    float*        hn      = (float*)(ws + WS_HN);
    _Float16*     hbuf    = (_Float16*)(ws + WS_HBUF);
    unsigned int* counter = (unsigned int*)(ws + WS_CTR);

    // zero k-split accumulators + barrier counter (ws/out are poisoned 0xAA)
    hipMemsetAsync(counter, 0, 64, stream);
    hipMemsetAsync(GX0, 0, 64 * 2048 * sizeof(float), stream);
    hipMemsetAsync(out, 0, 64 * 512 * sizeof(float), stream);

    // GX0 = x1 @ W_ih[:, :1024]^T + b_ih + b_hh    (K=1024, 4-way K-split)
    gemm_nt_bias<<<dim3(32, 1, 4), TPB, 0, stream>>>(
        x1, 1024, W_ih, 1152, GX0, 2048, 1024, b_ih, b_hh);
    // P = emb @ W_ih[:, 1024:]^T                   (K=128)
    gemm_nt_bias<<<dim3(32, 8, 1), TPB, 0, stream>>>(
        emb, 128, W_ih + 1024, 1152, P, 2048, 128, nullptr, nullptr);

    // recurrence: 64 WGs (1/CU, trivially co-resident), grid barrier per step
    lstm_seq<<<NWG, TPB, 0, stream>>>(W_hh, GX0, P, x2, lens, hbuf, hn, counter);

    // out = hn @ W_act^T + b_act                   (K=512, 4-way K-split)
    gemm_nt_bias<<<dim3(8, 1, 4), TPB, 0, stream>>>(
        hn, 512, W_act, 512, out, 512, 512, b_act, nullptr);
}